// Round 11
// baseline (398.425 us; speedup 1.0000x reference)
//
#include <hip/hip_runtime.h>

typedef unsigned int u32;
typedef unsigned short u16;
typedef unsigned long long u64;
typedef __attribute__((ext_vector_type(8))) short bf16x8;
typedef __attribute__((ext_vector_type(4))) float f32x4;

// ---------------- workspace layout (floats) ----------------
#define REL_OFF   0
#define PTS4_OFF  1572864   // pts4 during prep/knn; REUSED as W2 split after knn
#define ACC_OFF   1703936   // mom[16] | gsum8[512] | gsq8[512]  (1040 zeroed)
#define A1_OFF    1704976   // folded layer1 consts: [ch]{ax,ay,az,c} = 256 floats
#define S2_OFF    1705232   // 64
#define C2_OFF    1705296   // 64

__device__ __forceinline__ u32 bfh(float v){           // RNE bf16 hi bits
  u32 x = __float_as_uint(v);
  return (x + 0x7FFFu + ((x >> 16) & 1u)) >> 16;
}
__device__ __forceinline__ void split2(float v, u16* hh, u16* hl){
  u32 h = bfh(v);
  float hif = __uint_as_float(h << 16);
  u32 l = bfh(v - hif);
  *hh = (u16)h; *hl = (u16)l;
}

__global__ __launch_bounds__(256) void prep_kernel(const float* __restrict__ xyz,
                                                   float4* __restrict__ pts4){
#pragma clang fp contract(off)
  int g = blockIdx.x*256 + threadIdx.x;
  int b = g >> 12, n = g & 4095;
  const float* xb = xyz + (size_t)b*12288;
  float x = xb[n], y = xb[4096+n], z = xb[8192+n];
  float sq = (x*x + y*y) + z*z;
  pts4[g] = make_float4(x,y,z,sq);
}

// 48-bit key = (order-mapped f32 dist << 16) | u16(4095 - j), held EXACTLY in
// an f64 (52-bit mantissa): integer order == f64 order for nonneg values.
// Chain level = v_max_f64 + v_min_f64 (2 instr, mutually independent).
// Insert of 0.0 is a provable no-op (real keys >= 1).
__device__ __forceinline__ void chain_insert_d(double* s, double key){
  #pragma unroll
  for (int t=0;t<17;t++){
    double mx = fmax(s[t], key);
    key = fmin(s[t], key);
    s[t] = mx;
  }
}

// KNN. R10 structure (32-query blocks, 4 waves, half-wave splits, pipelined
// f64 chain, block-shared gate). R11 instruction cuts (time tracks VALU count):
//  - gate kept as mapped bits in LDS but UNMAPPED once per group to a float;
//    per-candidate test is `d >= gmin` -> the 3-op monotone map leaves the
//    512-candidate path (computed only on ~30 appends/lane).
//  - ring holds finished f64 keys (built at append): drain = 1 ds_read_b64,
//    no per-step cvt/mul/add reconstruction.
//  - pending refresh only when this group appended.
// NO __launch_bounds__ min-waves hint (R7/R8: any hint snaps to the 64-VGPR
// step and spills the chain to scratch).
__global__ __launch_bounds__(256) void knn_kernel(const float4* __restrict__ pts4,
                                                  float* __restrict__ rel,
                                                  float* __restrict__ mom){
#pragma clang fp contract(off)
  __shared__ double ring[4352];   // phase1: [tid*17 + slot] f64 keys (34816 B)
                                  // phase2 overlay: lA u32[4512] | lB u16[4512]
  __shared__ float bmom[16];
  __shared__ u32 gate[32];        // per-query mapped-bits lower bound on global 17th
  u32* lA = (u32*)ring;
  u16* lB = (u16*)((char*)ring + 18048);
  const int tid  = threadIdx.x;
  const int lane = tid & 63;
  const int wave = tid >> 6;          // 0..3
  const int q    = lane & 31;
  const int h    = lane >> 5;
  const int sp   = wave*2 + h;        // 0..7, candidate split
  const int blk  = blockIdx.x;        // 1024 = 8 batches * 128 query-groups
  const int b    = blk >> 7;
  const int q0   = (blk & 127) << 5;
  const float4* __restrict__ P = pts4 + ((size_t)b << 12);
  const float4* __restrict__ C = P + (sp << 9);
  const float4 me = P[q0 + q];
  if (tid < 16) bmom[tid] = 0.0f;
  if (tid < 32) gate[tid] = 0u;
  __syncthreads();

  double s[17];
  #pragma unroll
  for (int i=0;i<17;i++) s[i] = 0.0;
  const int base = tid*17;
  const int jg0 = sp << 9;            // global index base of this split
  u32 wr = 0, rd = 0;
  double pD_ = 0.0;                   // pending ring slot (prefetched)
  const double kinv = 1.52587890625e-05;   // 2^-16 (exact)

  // ---- warm-up: first 24 candidates inserted directly (fills depth-17 chain) ----
  for (int g8 = 0; g8 < 24; g8 += 8){
    float4 c[8];
    #pragma unroll
    for (int u=0;u<8;u++) c[u] = C[g8 + u];
    #pragma unroll
    for (int u=0;u<8;u++){
      const int j = jg0 + g8 + u;
      float dot = (me.x*c[u].x + me.y*c[u].y) + me.z*c[u].z;
      float d   = (me.w + c[u].w) - 2.0f*dot;
      u32 ub = __float_as_uint(d);
      ub ^= ((u32)(((int)ub) >> 31) | 0x80000000u);
      chain_insert_d(s, (double)ub * 65536.0 + (double)(4095 - j));
    }
  }
  u32 lastpub = (u32)(s[16] * kinv);
  atomicMax(&gate[q], lastpub);

  // pop pending into chain; immediately prefetch next slot (latency hidden by chain)
  #define INSERT_STEP() {                                        \
    bool act = rd != wr;                                         \
    double key = act ? pD_ : 0.0;                                \
    rd += act;                                                   \
    pD_ = ring[base + (int)(rd & 15u)];                          \
    if (__any(key > s[16])) chain_insert_d(s, key);              \
  }

  for (int g8 = 24; g8 < 512; g8 += 8){
    while (__any((int)(wr - rd) > 8)) INSERT_STEP();   // ensure >= 8 free slots
    float4 c[8];
    #pragma unroll
    for (int u=0;u<8;u++) c[u] = C[g8 + u];
    INSERT_STEP();
    const u32 ob = (u32)(s[16] * kinv);                // own 17th, mapped bits
    const u32 mb = max(gate[q], ob);
    const u32 ib = (mb >> 31) ? (mb ^ 0x80000000u) : ~mb;   // unmap (exact inverse)
    const float gmin = __uint_as_float(ib);
    const u32 wr0 = wr;
    #pragma unroll
    for (int u=0;u<8;u++){
      const int j = jg0 + g8 + u;
      float dot = (me.x*c[u].x + me.y*c[u].y) + me.z*c[u].z;
      float d   = (me.w + c[u].w) - 2.0f*dot;
      if (d >= gmin){                                  // == mapped >=, ties kept
        u32 ub = __float_as_uint(d);
        ub ^= ((u32)(((int)ub) >> 31) | 0x80000000u);
        ring[base + (int)(wr & 15u)] = (double)ub * 65536.0 + (double)(4095 - j);
        wr++;
      }
    }
    if (wr != wr0) pD_ = ring[base + (int)(rd & 15u)]; // refresh only if appended
    if (((g8 >> 3) & 3) == 3 && ob > lastpub){         // publish every 4th group
      atomicMax(&gate[q], ob);
      lastpub = ob;
    }
  }
  while (__any(rd != wr)) INSERT_STEP();               // final drain
  #undef INSERT_STEP

  __syncthreads();                    // ring dead; overlay LDS as sorted lists
  #pragma unroll
  for (int i=0;i<17;i++){
    const int o = (sp*17 + i)*33 + q;
    u32 hi = (u32)(s[i] * kinv);                       // exact: key = hi*2^16 + lo
    u32 lo = (u32)(s[i] - (double)hi * 65536.0);
    lA[o] = hi;
    lB[o] = (u16)lo;
  }
  __syncthreads();

  // 8-way merge, 8 lanes per query (256 threads = 32 queries x 8 subs).
  // Lists are disjoint candidate ranges -> keys unique, butterfly-max is exact.
  {
    const int mq  = tid >> 3;
    const int sub = tid & 7;
    const float4 qp = P[q0 + mq];
    float* __restrict__ ro = rel + (size_t)((b << 12) + q0 + mq) * 48;
    float sm0=0,sm1=0,sm2=0,sm3=0,sm4=0,sm5=0,sm6=0,sm7=0,sm8=0;
    int p = 0;
    for (int r=0;r<17;r++){
      const int idx = (sub*17 + p)*33 + mq;
      u64 mine = ((u64)lA[idx] << 16) | lB[idx];
      u64 kmax = mine;
      #pragma unroll
      for (int off=1; off<8; off<<=1){
        u64 o2 = __shfl_xor(kmax, off);
        kmax = (o2 > kmax) ? o2 : kmax;
      }
      p += (mine == kmax);
      if (r > 0 && sub == 0){   // drop rank 0 (the single farthest), keep 1..16
        const int j = 4095 - (int)(u32)(kmax & 0xFFFFull);
        const float4 nb = P[j];
        const float rx = nb.x - qp.x;
        const float ry = nb.y - qp.y;
        const float rz = nb.z - qp.z;
        ro[(r-1)*3+0] = rx; ro[(r-1)*3+1] = ry; ro[(r-1)*3+2] = rz;
        sm0 += rx; sm1 += ry; sm2 += rz;
        sm3 += rx*rx; sm4 += rx*ry; sm5 += rx*rz;
        sm6 += ry*ry; sm7 += ry*rz; sm8 += rz*rz;
      }
    }
    #pragma unroll
    for (int off=8; off<64; off<<=1){
      sm0 += __shfl_xor(sm0, off); sm1 += __shfl_xor(sm1, off); sm2 += __shfl_xor(sm2, off);
      sm3 += __shfl_xor(sm3, off); sm4 += __shfl_xor(sm4, off); sm5 += __shfl_xor(sm5, off);
      sm6 += __shfl_xor(sm6, off); sm7 += __shfl_xor(sm7, off); sm8 += __shfl_xor(sm8, off);
    }
    if (lane == 0){
      atomicAdd(&bmom[0], sm0); atomicAdd(&bmom[1], sm1); atomicAdd(&bmom[2], sm2);
      atomicAdd(&bmom[3], sm3); atomicAdd(&bmom[4], sm4); atomicAdd(&bmom[5], sm5);
      atomicAdd(&bmom[6], sm6); atomicAdd(&bmom[7], sm7); atomicAdd(&bmom[8], sm8);
    }
  }
  __syncthreads();
  if (tid < 9) atomicAdd(&mom[tid], bmom[tid]);
}

// BN1 analytic from rel moments; writes FOLDED layer1 consts a1[ch] = {s1*w1, s1*b1+t1}.
__global__ void stats1_kernel(const float* __restrict__ mom,
                              const float* __restrict__ w1, const float* __restrict__ b1,
                              const float* __restrict__ gamma, const float* __restrict__ beta,
                              float* __restrict__ a1){
  const int o = threadIdx.x;           // 64 threads
  const float Minv = 1.0f / 524288.0f;
  float m0 = mom[0]*Minv, m1 = mom[1]*Minv, m2 = mom[2]*Minv;
  float cxx = mom[3]*Minv - m0*m0;
  float cxy = mom[4]*Minv - m0*m1;
  float cxz = mom[5]*Minv - m0*m2;
  float cyy = mom[6]*Minv - m1*m1;
  float cyz = mom[7]*Minv - m1*m2;
  float czz = mom[8]*Minv - m2*m2;
  float wx = w1[o*3+0], wy = w1[o*3+1], wz = w1[o*3+2];
  float mu  = wx*m0 + wy*m1 + wz*m2 + b1[o];
  float var = wx*wx*cxx + wy*wy*cyy + wz*wz*czz
            + 2.0f*(wx*wy*cxy + wx*wz*cxz + wy*wz*cyz);
  float istd = rsqrtf(var + 1e-5f);
  float sc = gamma[o]*istd;
  float t1 = beta[o] - mu*sc;
  a1[o*4+0] = wx*sc;
  a1[o*4+1] = wy*sc;
  a1[o*4+2] = wz*sc;
  a1[o*4+3] = fmaf(sc, b1[o], t1);
}

// W2 bf16-split precompute, ONCE (was redone in LDS by all 4096 pass blocks).
// Writes into the dead pts4 region (knn has completed by launch order).
__global__ void w2prep_kernel(const float* __restrict__ w2,
                              u16* __restrict__ w2h, u16* __restrict__ w2l){
  int i = blockIdx.x*256 + threadIdx.x;   // 4096
  split2(w2[i], &w2h[i], &w2l[i]);
}

// ---- H1 staging: built from rel via folded layer1, packed 4-ch u64 LDS writes ----
__device__ __forceinline__ void stage_H(int tid, int blk,
    const float* __restrict__ rel, const float* __restrict__ a1,
    u16* Hh, u16* Hl){
  const int e = tid>>1, half = tid&1;
  size_t eg = (size_t)blk*128 + e;
  float rx = rel[eg*3+0], ry = rel[eg*3+1], rz = rel[eg*3+2];
  const float4* A1 = (const float4*)a1;
  const int ch0 = half*32;
  #pragma unroll
  for (int i=0;i<32;i+=4){
    u64 ph = 0, pl = 0;
    #pragma unroll
    for (int r2=0;r2<4;r2++){
      float4 a = A1[ch0+i+r2];
      float g = fmaf(a.x, rx, fmaf(a.y, ry, fmaf(a.z, rz, a.w)));
      g = fmaxf(g, 0.0f);
      u32 hb = bfh(g);
      u32 lb = bfh(g - __uint_as_float(hb << 16));
      ph |= ((u64)(u16)hb) << (16*r2);
      pl |= ((u64)(u16)lb) << (16*r2);
    }
    *(u64*)&Hh[e*72 + ch0 + i] = ph;
    *(u64*)&Hl[e*72 + ch0 + i] = pl;
  }
}

#define MFMA6(dst, b_h0, b_h1, b_l0, b_l1)                                   \
  dst = __builtin_amdgcn_mfma_f32_16x16x32_bf16(aH0, b_h0, dst, 0,0,0);      \
  dst = __builtin_amdgcn_mfma_f32_16x16x32_bf16(aH1, b_h1, dst, 0,0,0);      \
  dst = __builtin_amdgcn_mfma_f32_16x16x32_bf16(aH0, b_l0, dst, 0,0,0);      \
  dst = __builtin_amdgcn_mfma_f32_16x16x32_bf16(aH1, b_l1, dst, 0,0,0);      \
  dst = __builtin_amdgcn_mfma_f32_16x16x32_bf16(aL0, b_h0, dst, 0,0,0);      \
  dst = __builtin_amdgcn_mfma_f32_16x16x32_bf16(aL1, b_h1, dst, 0,0,0);

#define LOAD_W_FRAGS()                                                        \
  const int rA = (wave*16 + col)*64 + quad*8;                                 \
  bf16x8 aH0 = *(const bf16x8*)&w2h[rA];                                      \
  bf16x8 aH1 = *(const bf16x8*)&w2h[rA+32];                                   \
  bf16x8 aL0 = *(const bf16x8*)&w2l[rA];                                      \
  bf16x8 aL1 = *(const bf16x8*)&w2l[rA+32];

// Pass 2 (MFMA): g2 = W2@H1 + b2; per-channel sum/sumsq into 8-way-striped
// global accumulators. LDS = H only (36.9 KB -> 4 blocks/CU).
__global__ __launch_bounds__(256) void pass2_mfma(
    const float* __restrict__ rel, const float* __restrict__ a1,
    const u16* __restrict__ w2h, const u16* __restrict__ w2l,
    const float* __restrict__ b2,
    float* __restrict__ gsum8, float* __restrict__ gsq8){
  __shared__ alignas(16) u16 Hh[128*72], Hl[128*72];
  const int tid = threadIdx.x, blk = blockIdx.x;
  stage_H(tid, blk, rel, a1, Hh, Hl);
  __syncthreads();
  const int lane = tid & 63, wave = tid >> 6;
  const int col = lane & 15, quad = lane >> 4;
  LOAD_W_FRAGS()
  float b2v[4];
  #pragma unroll
  for (int r=0;r<4;r++) b2v[r] = b2[wave*16 + quad*4 + r];
  float ssum[4] = {0,0,0,0}, ssq[4] = {0,0,0,0};
  #pragma unroll
  for (int nt=0; nt<8; nt++){
    const int offB = (nt*16 + col)*72 + quad*8;
    bf16x8 bH0 = *(const bf16x8*)&Hh[offB];
    bf16x8 bH1 = *(const bf16x8*)&Hh[offB+32];
    bf16x8 bL0 = *(const bf16x8*)&Hl[offB];
    bf16x8 bL1 = *(const bf16x8*)&Hl[offB+32];
    f32x4 a = {0.f,0.f,0.f,0.f};
    MFMA6(a, bH0, bH1, bL0, bL1)
    #pragma unroll
    for (int r=0;r<4;r++){
      float t = a[r] + b2v[r];
      ssum[r] += t; ssq[r] += t*t;
    }
  }
  #pragma unroll
  for (int off=1; off<16; off<<=1){
    #pragma unroll
    for (int r=0;r<4;r++){
      ssum[r] += __shfl_xor(ssum[r], off);
      ssq[r]  += __shfl_xor(ssq[r],  off);
    }
  }
  if (col == 0){
    const int st = (blk & 7)*64;
    #pragma unroll
    for (int r=0;r<4;r++){
      int ch = wave*16 + quad*4 + r;
      atomicAdd(&gsum8[st+ch], ssum[r]);
      atomicAdd(&gsq8[st+ch],  ssq[r]);
    }
  }
}

// BN2 consts from striped sums: s2 = gamma*istd, c2 = s2*b2 + (beta - mu*s2).
__global__ void stats2_kernel(const float* __restrict__ gsum8, const float* __restrict__ gsq8,
                              const float* __restrict__ b2,
                              const float* __restrict__ gamma, const float* __restrict__ beta,
                              float* __restrict__ s2a, float* __restrict__ c2a){
  const int o = threadIdx.x;
  float s = 0.f, q = 0.f;
  #pragma unroll
  for (int i=0;i<8;i++){ s += gsum8[i*64+o]; q += gsq8[i*64+o]; }
  const float Minv = 1.0f / 524288.0f;
  float mu  = s*Minv;
  float var = q*Minv - mu*mu;
  float istd = rsqrtf(var + 1e-5f);
  float sc = gamma[o]*istd;
  float t2 = beta[o] - mu*sc;
  s2a[o] = sc;
  c2a[o] = fmaf(sc, b2[o], t2);
}

// Pass 3 (MFMA): H1 -> g2 -> (BN2+relu) H2 (overwrites H1 in LDS) -> g3 -> max over k.
__global__ __launch_bounds__(256) void pass3_mfma(
    const float* __restrict__ rel, const float* __restrict__ a1,
    const u16* __restrict__ w2h, const u16* __restrict__ w2l,
    const float* __restrict__ b2,
    const float* __restrict__ s2a, const float* __restrict__ c2a,
    float* __restrict__ out){
  __shared__ alignas(16) u16 Hh[128*72], Hl[128*72];
  const int tid = threadIdx.x, blk = blockIdx.x;
  stage_H(tid, blk, rel, a1, Hh, Hl);
  __syncthreads();
  const int lane = tid & 63, wave = tid >> 6;
  const int col = lane & 15, quad = lane >> 4;
  LOAD_W_FRAGS()
  float s2v[4], c2v[4], b2v[4];
  #pragma unroll
  for (int r=0;r<4;r++){
    int ch = wave*16 + quad*4 + r;
    s2v[r] = s2a[ch]; c2v[r] = c2a[ch]; b2v[r] = b2[ch];
  }
  f32x4 acc[8];
  #pragma unroll
  for (int nt=0; nt<8; nt++){
    const int offB = (nt*16 + col)*72 + quad*8;
    bf16x8 bH0 = *(const bf16x8*)&Hh[offB];
    bf16x8 bH1 = *(const bf16x8*)&Hh[offB+32];
    bf16x8 bL0 = *(const bf16x8*)&Hl[offB];
    bf16x8 bL1 = *(const bf16x8*)&Hl[offB+32];
    f32x4 a = {0.f,0.f,0.f,0.f};
    MFMA6(a, bH0, bH1, bL0, bL1)
    acc[nt] = a;
  }
  __syncthreads();   // all layer-2 H reads done -> safe to overwrite with H2
  #pragma unroll
  for (int nt=0; nt<8; nt++){
    const int e = nt*16 + col;
    const int ch0 = wave*16 + quad*4;
    u64 ph = 0, pl = 0;
    #pragma unroll
    for (int r=0;r<4;r++){
      float g = acc[nt][r] + b2v[r];
      float h = fmaxf(fmaf(g, s2v[r], c2v[r]), 0.0f);
      u32 hb = bfh(h);
      u32 lb = bfh(h - __uint_as_float(hb << 16));
      ph |= ((u64)hb) << (16*r);
      pl |= ((u64)lb) << (16*r);
    }
    *(u64*)&Hh[e*72 + ch0] = ph;
    *(u64*)&Hl[e*72 + ch0] = pl;
  }
  __syncthreads();
  #pragma unroll
  for (int nt=0; nt<8; nt++){
    const int offB = (nt*16 + col)*72 + quad*8;
    bf16x8 bH0 = *(const bf16x8*)&Hh[offB];
    bf16x8 bH1 = *(const bf16x8*)&Hh[offB+32];
    bf16x8 bL0 = *(const bf16x8*)&Hl[offB];
    bf16x8 bL1 = *(const bf16x8*)&Hl[offB+32];
    f32x4 a = {0.f,0.f,0.f,0.f};
    MFMA6(a, bH0, bH1, bL0, bL1)
    float m0 = a[0]+b2v[0], m1 = a[1]+b2v[1], m2 = a[2]+b2v[2], m3 = a[3]+b2v[3];
    #pragma unroll
    for (int off=1; off<16; off<<=1){
      m0 = fmaxf(m0, __shfl_xor(m0, off));
      m1 = fmaxf(m1, __shfl_xor(m1, off));
      m2 = fmaxf(m2, __shfl_xor(m2, off));
      m3 = fmaxf(m3, __shfl_xor(m3, off));
    }
    if (col == 0){
      const int gp = blk*8 + nt;
      const int b = gp >> 12, n = gp & 4095;
      const int ch0 = wave*16 + quad*4;
      size_t o0 = (((size_t)b*64 + ch0) << 12) + n;
      out[o0]         = m0;
      out[o0 + 4096]  = m1;
      out[o0 + 8192]  = m2;
      out[o0 + 12288] = m3;
    }
  }
}

extern "C" void kernel_launch(void* const* d_in, const int* in_sizes, int n_in,
                              void* d_out, int out_size, void* d_ws, size_t ws_size,
                              hipStream_t stream){
  const float* xyz   = (const float*)d_in[0];
  const float* w1    = (const float*)d_in[1];
  const float* b1    = (const float*)d_in[2];
  const float* w2    = (const float*)d_in[3];
  const float* b2    = (const float*)d_in[4];
  const float* gamma = (const float*)d_in[5];
  const float* beta  = (const float*)d_in[6];
  float* out = (float*)d_out;
  float* ws  = (float*)d_ws;

  float*  rel   = ws + REL_OFF;
  float4* pts4  = (float4*)(ws + PTS4_OFF);
  u16*    w2h   = (u16*)(ws + PTS4_OFF);          // reuses dead pts4 (after knn)
  u16*    w2l   = (u16*)(ws + PTS4_OFF + 2048);
  float*  mom   = ws + ACC_OFF;        // 16
  float*  gsum8 = mom + 16;            // 512
  float*  gsq8  = mom + 528;           // 512
  float*  a1    = ws + A1_OFF;         // 256
  float*  s2a   = ws + S2_OFF;         // 64
  float*  c2a   = ws + C2_OFF;         // 64

  hipMemsetAsync(mom, 0, 1040*sizeof(float), stream);
  prep_kernel  <<<128,  256, 0, stream>>>(xyz, pts4);
  knn_kernel   <<<1024, 256, 0, stream>>>(pts4, rel, mom);
  stats1_kernel<<<1,     64, 0, stream>>>(mom, w1, b1, gamma, beta, a1);
  w2prep_kernel<<<16,   256, 0, stream>>>(w2, w2h, w2l);
  pass2_mfma   <<<4096, 256, 0, stream>>>(rel, a1, w2h, w2l, b2, gsum8, gsq8);
  stats2_kernel<<<1,     64, 0, stream>>>(gsum8, gsq8, b2, gamma, beta, s2a, c2a);
  pass3_mfma   <<<4096, 256, 0, stream>>>(rel, a1, w2h, w2l, b2, s2a, c2a, out);
}

// Round 12
// 369.526 us; speedup vs baseline: 1.0782x; 1.0782x over previous
//
#include <hip/hip_runtime.h>

typedef unsigned int u32;
typedef unsigned short u16;
typedef unsigned long long u64;
typedef __attribute__((ext_vector_type(8))) short bf16x8;
typedef __attribute__((ext_vector_type(4))) float f32x4;

// ---------------- workspace layout (floats) ----------------
#define REL_OFF   0
#define PTS4_OFF  1572864   // pts4 during prep/knn; REUSED after knn:
                            //   w2h/w2l (4096 fl) | gsum32[2048] | gsq32[2048]
#define ACC_OFF   1703936   // mom[16]  (zeroed at stream start)
#define A1_OFF    1704976   // folded layer1 consts: [ch]{ax,ay,az,c} = 256 floats
#define S2_OFF    1705232   // 64
#define C2_OFF    1705296   // 64

__device__ __forceinline__ u32 bfh(float v){           // RNE bf16 hi bits
  u32 x = __float_as_uint(v);
  return (x + 0x7FFFu + ((x >> 16) & 1u)) >> 16;
}
__device__ __forceinline__ void split2(float v, u16* hh, u16* hl){
  u32 h = bfh(v);
  float hif = __uint_as_float(h << 16);
  u32 l = bfh(v - hif);
  *hh = (u16)h; *hl = (u16)l;
}

__global__ __launch_bounds__(256) void prep_kernel(const float* __restrict__ xyz,
                                                   float4* __restrict__ pts4){
#pragma clang fp contract(off)
  int g = blockIdx.x*256 + threadIdx.x;
  int b = g >> 12, n = g & 4095;
  const float* xb = xyz + (size_t)b*12288;
  float x = xb[n], y = xb[4096+n], z = xb[8192+n];
  float sq = (x*x + y*y) + z*z;
  pts4[g] = make_float4(x,y,z,sq);
}

// 48-bit key = (order-mapped f32 dist << 16) | u16(4095 - j), held EXACTLY in
// an f64 (52-bit mantissa). Chain level = v_max_f64 + v_min_f64.
__device__ __forceinline__ void chain_insert_d(double* s, double key){
  #pragma unroll
  for (int t=0;t<17;t++){
    double mx = fmax(s[t], key);
    key = fmin(s[t], key);
    s[t] = mx;
  }
}

// KNN: UNCHANGED from R11 (219 us; three structural attacks all landed ~219 ->
// structural floor for this algorithm). No min-waves hint (R7/R8 spill lesson).
__global__ __launch_bounds__(256) void knn_kernel(const float4* __restrict__ pts4,
                                                  float* __restrict__ rel,
                                                  float* __restrict__ mom){
#pragma clang fp contract(off)
  __shared__ double ring[4352];
  __shared__ float bmom[16];
  __shared__ u32 gate[32];
  u32* lA = (u32*)ring;
  u16* lB = (u16*)((char*)ring + 18048);
  const int tid  = threadIdx.x;
  const int lane = tid & 63;
  const int wave = tid >> 6;
  const int q    = lane & 31;
  const int h    = lane >> 5;
  const int sp   = wave*2 + h;
  const int blk  = blockIdx.x;
  const int b    = blk >> 7;
  const int q0   = (blk & 127) << 5;
  const float4* __restrict__ P = pts4 + ((size_t)b << 12);
  const float4* __restrict__ C = P + (sp << 9);
  const float4 me = P[q0 + q];
  if (tid < 16) bmom[tid] = 0.0f;
  if (tid < 32) gate[tid] = 0u;
  __syncthreads();

  double s[17];
  #pragma unroll
  for (int i=0;i<17;i++) s[i] = 0.0;
  const int base = tid*17;
  const int jg0 = sp << 9;
  u32 wr = 0, rd = 0;
  double pD_ = 0.0;
  const double kinv = 1.52587890625e-05;

  for (int g8 = 0; g8 < 24; g8 += 8){
    float4 c[8];
    #pragma unroll
    for (int u=0;u<8;u++) c[u] = C[g8 + u];
    #pragma unroll
    for (int u=0;u<8;u++){
      const int j = jg0 + g8 + u;
      float dot = (me.x*c[u].x + me.y*c[u].y) + me.z*c[u].z;
      float d   = (me.w + c[u].w) - 2.0f*dot;
      u32 ub = __float_as_uint(d);
      ub ^= ((u32)(((int)ub) >> 31) | 0x80000000u);
      chain_insert_d(s, (double)ub * 65536.0 + (double)(4095 - j));
    }
  }
  u32 lastpub = (u32)(s[16] * kinv);
  atomicMax(&gate[q], lastpub);

  #define INSERT_STEP() {                                        \
    bool act = rd != wr;                                         \
    double key = act ? pD_ : 0.0;                                \
    rd += act;                                                   \
    pD_ = ring[base + (int)(rd & 15u)];                          \
    if (__any(key > s[16])) chain_insert_d(s, key);              \
  }

  for (int g8 = 24; g8 < 512; g8 += 8){
    while (__any((int)(wr - rd) > 8)) INSERT_STEP();
    float4 c[8];
    #pragma unroll
    for (int u=0;u<8;u++) c[u] = C[g8 + u];
    INSERT_STEP();
    const u32 ob = (u32)(s[16] * kinv);
    const u32 mb = max(gate[q], ob);
    const u32 ib = (mb >> 31) ? (mb ^ 0x80000000u) : ~mb;
    const float gmin = __uint_as_float(ib);
    const u32 wr0 = wr;
    #pragma unroll
    for (int u=0;u<8;u++){
      const int j = jg0 + g8 + u;
      float dot = (me.x*c[u].x + me.y*c[u].y) + me.z*c[u].z;
      float d   = (me.w + c[u].w) - 2.0f*dot;
      if (d >= gmin){
        u32 ub = __float_as_uint(d);
        ub ^= ((u32)(((int)ub) >> 31) | 0x80000000u);
        ring[base + (int)(wr & 15u)] = (double)ub * 65536.0 + (double)(4095 - j);
        wr++;
      }
    }
    if (wr != wr0) pD_ = ring[base + (int)(rd & 15u)];
    if (((g8 >> 3) & 3) == 3 && ob > lastpub){
      atomicMax(&gate[q], ob);
      lastpub = ob;
    }
  }
  while (__any(rd != wr)) INSERT_STEP();
  #undef INSERT_STEP

  __syncthreads();
  #pragma unroll
  for (int i=0;i<17;i++){
    const int o = (sp*17 + i)*33 + q;
    u32 hi = (u32)(s[i] * kinv);
    u32 lo = (u32)(s[i] - (double)hi * 65536.0);
    lA[o] = hi;
    lB[o] = (u16)lo;
  }
  __syncthreads();

  {
    const int mq  = tid >> 3;
    const int sub = tid & 7;
    const float4 qp = P[q0 + mq];
    float* __restrict__ ro = rel + (size_t)((b << 12) + q0 + mq) * 48;
    float sm0=0,sm1=0,sm2=0,sm3=0,sm4=0,sm5=0,sm6=0,sm7=0,sm8=0;
    int p = 0;
    for (int r=0;r<17;r++){
      const int idx = (sub*17 + p)*33 + mq;
      u64 mine = ((u64)lA[idx] << 16) | lB[idx];
      u64 kmax = mine;
      #pragma unroll
      for (int off=1; off<8; off<<=1){
        u64 o2 = __shfl_xor(kmax, off);
        kmax = (o2 > kmax) ? o2 : kmax;
      }
      p += (mine == kmax);
      if (r > 0 && sub == 0){
        const int j = 4095 - (int)(u32)(kmax & 0xFFFFull);
        const float4 nb = P[j];
        const float rx = nb.x - qp.x;
        const float ry = nb.y - qp.y;
        const float rz = nb.z - qp.z;
        ro[(r-1)*3+0] = rx; ro[(r-1)*3+1] = ry; ro[(r-1)*3+2] = rz;
        sm0 += rx; sm1 += ry; sm2 += rz;
        sm3 += rx*rx; sm4 += rx*ry; sm5 += rx*rz;
        sm6 += ry*ry; sm7 += ry*rz; sm8 += rz*rz;
      }
    }
    #pragma unroll
    for (int off=8; off<64; off<<=1){
      sm0 += __shfl_xor(sm0, off); sm1 += __shfl_xor(sm1, off); sm2 += __shfl_xor(sm2, off);
      sm3 += __shfl_xor(sm3, off); sm4 += __shfl_xor(sm4, off); sm5 += __shfl_xor(sm5, off);
      sm6 += __shfl_xor(sm6, off); sm7 += __shfl_xor(sm7, off); sm8 += __shfl_xor(sm8, off);
    }
    if (lane == 0){
      atomicAdd(&bmom[0], sm0); atomicAdd(&bmom[1], sm1); atomicAdd(&bmom[2], sm2);
      atomicAdd(&bmom[3], sm3); atomicAdd(&bmom[4], sm4); atomicAdd(&bmom[5], sm5);
      atomicAdd(&bmom[6], sm6); atomicAdd(&bmom[7], sm7); atomicAdd(&bmom[8], sm8);
    }
  }
  __syncthreads();
  if (tid < 9) atomicAdd(&mom[tid], bmom[tid]);
}

// BN1 analytic; writes folded layer1 consts a1[ch] = {s1*w1, s1*b1+t1}.
__global__ void stats1_kernel(const float* __restrict__ mom,
                              const float* __restrict__ w1, const float* __restrict__ b1,
                              const float* __restrict__ gamma, const float* __restrict__ beta,
                              float* __restrict__ a1){
  const int o = threadIdx.x;
  const float Minv = 1.0f / 524288.0f;
  float m0 = mom[0]*Minv, m1 = mom[1]*Minv, m2 = mom[2]*Minv;
  float cxx = mom[3]*Minv - m0*m0;
  float cxy = mom[4]*Minv - m0*m1;
  float cxz = mom[5]*Minv - m0*m2;
  float cyy = mom[6]*Minv - m1*m1;
  float cyz = mom[7]*Minv - m1*m2;
  float czz = mom[8]*Minv - m2*m2;
  float wx = w1[o*3+0], wy = w1[o*3+1], wz = w1[o*3+2];
  float mu  = wx*m0 + wy*m1 + wz*m2 + b1[o];
  float var = wx*wx*cxx + wy*wy*cyy + wz*wz*czz
            + 2.0f*(wx*wy*cxy + wx*wz*cxz + wy*wz*cyz);
  float istd = rsqrtf(var + 1e-5f);
  float sc = gamma[o]*istd;
  float t1 = beta[o] - mu*sc;
  a1[o*4+0] = wx*sc;
  a1[o*4+1] = wy*sc;
  a1[o*4+2] = wz*sc;
  a1[o*4+3] = fmaf(sc, b1[o], t1);
}

// W2 bf16-split precompute, once (into dead pts4 region).
__global__ void w2prep_kernel(const float* __restrict__ w2,
                              u16* __restrict__ w2h, u16* __restrict__ w2l){
  int i = blockIdx.x*256 + threadIdx.x;   // 4096
  split2(w2[i], &w2h[i], &w2l[i]);
}

// ---- H1 staging: built from rel via folded layer1, packed 4-ch u64 LDS writes ----
__device__ __forceinline__ void stage_H(int tid, int blk,
    const float* __restrict__ rel, const float* __restrict__ a1,
    u16* Hh, u16* Hl){
  const int e = tid>>1, half = tid&1;
  size_t eg = (size_t)blk*128 + e;
  float rx = rel[eg*3+0], ry = rel[eg*3+1], rz = rel[eg*3+2];
  const float4* A1 = (const float4*)a1;
  const int ch0 = half*32;
  #pragma unroll
  for (int i=0;i<32;i+=4){
    u64 ph = 0, pl = 0;
    #pragma unroll
    for (int r2=0;r2<4;r2++){
      float4 a = A1[ch0+i+r2];
      float g = fmaf(a.x, rx, fmaf(a.y, ry, fmaf(a.z, rz, a.w)));
      g = fmaxf(g, 0.0f);
      u32 hb = bfh(g);
      u32 lb = bfh(g - __uint_as_float(hb << 16));
      ph |= ((u64)(u16)hb) << (16*r2);
      pl |= ((u64)(u16)lb) << (16*r2);
    }
    *(u64*)&Hh[e*72 + ch0 + i] = ph;
    *(u64*)&Hl[e*72 + ch0 + i] = pl;
  }
}

#define MFMA6(dst, b_h0, b_h1, b_l0, b_l1)                                   \
  dst = __builtin_amdgcn_mfma_f32_16x16x32_bf16(aH0, b_h0, dst, 0,0,0);      \
  dst = __builtin_amdgcn_mfma_f32_16x16x32_bf16(aH1, b_h1, dst, 0,0,0);      \
  dst = __builtin_amdgcn_mfma_f32_16x16x32_bf16(aH0, b_l0, dst, 0,0,0);      \
  dst = __builtin_amdgcn_mfma_f32_16x16x32_bf16(aH1, b_l1, dst, 0,0,0);      \
  dst = __builtin_amdgcn_mfma_f32_16x16x32_bf16(aL0, b_h0, dst, 0,0,0);      \
  dst = __builtin_amdgcn_mfma_f32_16x16x32_bf16(aL1, b_h1, dst, 0,0,0);

#define LOAD_W_FRAGS()                                                        \
  const int rA = (wave*16 + col)*64 + quad*8;                                 \
  bf16x8 aH0 = *(const bf16x8*)&w2h[rA];                                      \
  bf16x8 aH1 = *(const bf16x8*)&w2h[rA+32];                                   \
  bf16x8 aL0 = *(const bf16x8*)&w2l[rA];                                      \
  bf16x8 aL1 = *(const bf16x8*)&w2l[rA+32];

// Pass 2 (MFMA): g2 = W2@H1 + b2; per-channel sum/sumsq into 32-way-striped
// global accumulators (R12: contention /4 vs 8-way; 4096 addresses).
__global__ __launch_bounds__(256) void pass2_mfma(
    const float* __restrict__ rel, const float* __restrict__ a1,
    const u16* __restrict__ w2h, const u16* __restrict__ w2l,
    const float* __restrict__ b2,
    float* __restrict__ gsum32, float* __restrict__ gsq32){
  __shared__ alignas(16) u16 Hh[128*72], Hl[128*72];
  const int tid = threadIdx.x, blk = blockIdx.x;
  stage_H(tid, blk, rel, a1, Hh, Hl);
  __syncthreads();
  const int lane = tid & 63, wave = tid >> 6;
  const int col = lane & 15, quad = lane >> 4;
  LOAD_W_FRAGS()
  float b2v[4];
  #pragma unroll
  for (int r=0;r<4;r++) b2v[r] = b2[wave*16 + quad*4 + r];
  float ssum[4] = {0,0,0,0}, ssq[4] = {0,0,0,0};
  #pragma unroll
  for (int nt=0; nt<8; nt++){
    const int offB = (nt*16 + col)*72 + quad*8;
    bf16x8 bH0 = *(const bf16x8*)&Hh[offB];
    bf16x8 bH1 = *(const bf16x8*)&Hh[offB+32];
    bf16x8 bL0 = *(const bf16x8*)&Hl[offB];
    bf16x8 bL1 = *(const bf16x8*)&Hl[offB+32];
    f32x4 a = {0.f,0.f,0.f,0.f};
    MFMA6(a, bH0, bH1, bL0, bL1)
    #pragma unroll
    for (int r=0;r<4;r++){
      float t = a[r] + b2v[r];
      ssum[r] += t; ssq[r] += t*t;
    }
  }
  #pragma unroll
  for (int off=1; off<16; off<<=1){
    #pragma unroll
    for (int r=0;r<4;r++){
      ssum[r] += __shfl_xor(ssum[r], off);
      ssq[r]  += __shfl_xor(ssq[r],  off);
    }
  }
  if (col == 0){
    const int st = (blk & 31)*64;
    #pragma unroll
    for (int r=0;r<4;r++){
      int ch = wave*16 + quad*4 + r;
      atomicAdd(&gsum32[st+ch], ssum[r]);
      atomicAdd(&gsq32[st+ch],  ssq[r]);
    }
  }
}

// BN2 consts from 32-way striped sums.
__global__ void stats2_kernel(const float* __restrict__ gsum32, const float* __restrict__ gsq32,
                              const float* __restrict__ b2,
                              const float* __restrict__ gamma, const float* __restrict__ beta,
                              float* __restrict__ s2a, float* __restrict__ c2a){
  const int o = threadIdx.x;
  float s = 0.f, q = 0.f;
  #pragma unroll
  for (int i=0;i<32;i++){ s += gsum32[i*64+o]; q += gsq32[i*64+o]; }
  const float Minv = 1.0f / 524288.0f;
  float mu  = s*Minv;
  float var = q*Minv - mu*mu;
  float istd = rsqrtf(var + 1e-5f);
  float sc = gamma[o]*istd;
  float t2 = beta[o] - mu*sc;
  s2a[o] = sc;
  c2a[o] = fmaf(sc, b2[o], t2);
}

// Pass 3 (MFMA): H1 -> g2 -> (BN2+relu) H2 -> g3 -> max over k.
// R12: maxima buffered in the dead acc[] registers, then stored as 2x dwordx4
// of 8 consecutive n per channel (was: 4B stores at 16 KB stride -> ~64-128 MB
// effective HBM write traffic; now 8 MB coalesced).
__global__ __launch_bounds__(256) void pass3_mfma(
    const float* __restrict__ rel, const float* __restrict__ a1,
    const u16* __restrict__ w2h, const u16* __restrict__ w2l,
    const float* __restrict__ b2,
    const float* __restrict__ s2a, const float* __restrict__ c2a,
    float* __restrict__ out){
  __shared__ alignas(16) u16 Hh[128*72], Hl[128*72];
  const int tid = threadIdx.x, blk = blockIdx.x;
  stage_H(tid, blk, rel, a1, Hh, Hl);
  __syncthreads();
  const int lane = tid & 63, wave = tid >> 6;
  const int col = lane & 15, quad = lane >> 4;
  LOAD_W_FRAGS()
  float s2v[4], c2v[4], b2v[4];
  #pragma unroll
  for (int r=0;r<4;r++){
    int ch = wave*16 + quad*4 + r;
    s2v[r] = s2a[ch]; c2v[r] = c2a[ch]; b2v[r] = b2[ch];
  }
  f32x4 acc[8];
  #pragma unroll
  for (int nt=0; nt<8; nt++){
    const int offB = (nt*16 + col)*72 + quad*8;
    bf16x8 bH0 = *(const bf16x8*)&Hh[offB];
    bf16x8 bH1 = *(const bf16x8*)&Hh[offB+32];
    bf16x8 bL0 = *(const bf16x8*)&Hl[offB];
    bf16x8 bL1 = *(const bf16x8*)&Hl[offB+32];
    f32x4 a = {0.f,0.f,0.f,0.f};
    MFMA6(a, bH0, bH1, bL0, bL1)
    acc[nt] = a;
  }
  __syncthreads();   // all layer-2 H reads done -> safe to overwrite with H2
  #pragma unroll
  for (int nt=0; nt<8; nt++){
    const int e = nt*16 + col;
    const int ch0 = wave*16 + quad*4;
    u64 ph = 0, pl = 0;
    #pragma unroll
    for (int r=0;r<4;r++){
      float g = acc[nt][r] + b2v[r];
      float h = fmaxf(fmaf(g, s2v[r], c2v[r]), 0.0f);
      u32 hb = bfh(h);
      u32 lb = bfh(h - __uint_as_float(hb << 16));
      ph |= ((u64)hb) << (16*r);
      pl |= ((u64)lb) << (16*r);
    }
    *(u64*)&Hh[e*72 + ch0] = ph;
    *(u64*)&Hl[e*72 + ch0] = pl;
  }
  __syncthreads();
  #pragma unroll
  for (int nt=0; nt<8; nt++){
    const int offB = (nt*16 + col)*72 + quad*8;
    bf16x8 bH0 = *(const bf16x8*)&Hh[offB];
    bf16x8 bH1 = *(const bf16x8*)&Hh[offB+32];
    bf16x8 bL0 = *(const bf16x8*)&Hl[offB];
    bf16x8 bL1 = *(const bf16x8*)&Hl[offB+32];
    f32x4 a = {0.f,0.f,0.f,0.f};
    MFMA6(a, bH0, bH1, bL0, bL1)
    float m0 = a[0]+b2v[0], m1 = a[1]+b2v[1], m2 = a[2]+b2v[2], m3 = a[3]+b2v[3];
    #pragma unroll
    for (int off=1; off<16; off<<=1){
      m0 = fmaxf(m0, __shfl_xor(m0, off));
      m1 = fmaxf(m1, __shfl_xor(m1, off));
      m2 = fmaxf(m2, __shfl_xor(m2, off));
      m3 = fmaxf(m3, __shfl_xor(m3, off));
    }
    acc[nt][0] = m0; acc[nt][1] = m1; acc[nt][2] = m2; acc[nt][3] = m3;
  }
  if (col == 0){
    const int bb = blk >> 9;
    const int n0 = (blk & 511) * 8;
    #pragma unroll
    for (int r=0;r<4;r++){
      const int ch = wave*16 + quad*4 + r;
      float* po = out + (((size_t)bb*64 + ch) << 12) + n0;
      f32x4 v0 = {acc[0][r], acc[1][r], acc[2][r], acc[3][r]};
      f32x4 v1 = {acc[4][r], acc[5][r], acc[6][r], acc[7][r]};
      *(f32x4*)po = v0;
      *((f32x4*)po + 1) = v1;
    }
  }
}

extern "C" void kernel_launch(void* const* d_in, const int* in_sizes, int n_in,
                              void* d_out, int out_size, void* d_ws, size_t ws_size,
                              hipStream_t stream){
  const float* xyz   = (const float*)d_in[0];
  const float* w1    = (const float*)d_in[1];
  const float* b1    = (const float*)d_in[2];
  const float* w2    = (const float*)d_in[3];
  const float* b2    = (const float*)d_in[4];
  const float* gamma = (const float*)d_in[5];
  const float* beta  = (const float*)d_in[6];
  float* out = (float*)d_out;
  float* ws  = (float*)d_ws;

  float*  rel    = ws + REL_OFF;
  float4* pts4   = (float4*)(ws + PTS4_OFF);
  u16*    w2h    = (u16*)(ws + PTS4_OFF);          // dead pts4 (after knn)
  u16*    w2l    = (u16*)(ws + PTS4_OFF + 2048);
  float*  gsum32 = ws + PTS4_OFF + 4096;           // 2048, zeroed after knn
  float*  gsq32  = ws + PTS4_OFF + 6144;           // 2048
  float*  mom    = ws + ACC_OFF;       // 16
  float*  a1     = ws + A1_OFF;        // 256
  float*  s2a    = ws + S2_OFF;        // 64
  float*  c2a    = ws + C2_OFF;        // 64

  hipMemsetAsync(mom, 0, 16*sizeof(float), stream);
  prep_kernel  <<<128,  256, 0, stream>>>(xyz, pts4);
  knn_kernel   <<<1024, 256, 0, stream>>>(pts4, rel, mom);
  stats1_kernel<<<1,     64, 0, stream>>>(mom, w1, b1, gamma, beta, a1);
  w2prep_kernel<<<16,   256, 0, stream>>>(w2, w2h, w2l);
  hipMemsetAsync(gsum32, 0, 4096*sizeof(float), stream);   // stream-ordered: after knn
  pass2_mfma   <<<4096, 256, 0, stream>>>(rel, a1, w2h, w2l, b2, gsum32, gsq32);
  stats2_kernel<<<1,     64, 0, stream>>>(gsum32, gsq32, b2, gamma, beta, s2a, c2a);
  pass3_mfma   <<<4096, 256, 0, stream>>>(rel, a1, w2h, w2l, b2, s2a, c2a, out);
}